// Round 6
// baseline (528.313 us; speedup 1.0000x reference)
//
#include <hip/hip_runtime.h>

// ---------------------------------------------------------------------------
// EdgeModel: out = LayerNorm(LReLU(LReLU(LReLU(X@W1+b1)@W2+b2)@W3+b3))
// X = concat[src, dest, edge_attr, u[batch]]  (E=400000, 512 features)
// R6: isolate TLP at fixed weight traffic. M_TILE=64, 8 waves (512 thr,
//     2Mx4N, wave tile 32x64 -> acc[2][4]=32). No launch_bounds reg cap
//     (R2/R4/R5: any cap below natural demand spills). LDS 48KB -> 2
//     blocks/CU = 16 waves/CU, same 2.8GB weight-L2 stream as R3.
// ---------------------------------------------------------------------------

typedef short bf16x8 __attribute__((ext_vector_type(8)));   // 8 bf16 (guide §3)
typedef float f32x4 __attribute__((ext_vector_type(4)));
typedef unsigned short us4 __attribute__((ext_vector_type(4)));

__device__ __forceinline__ unsigned short f2bf(float f) {  // RNE f32->bf16
    union { float f; unsigned u; } v; v.f = f;
    return (unsigned short)((v.u + 0x7fffu + ((v.u >> 16) & 1u)) >> 16);
}
__device__ __forceinline__ float lrelu(float v) { return v >= 0.f ? v : 0.01f * v; }

// ---------------------------------------------------------------------------
// Pack W (K x N, row-major f32) into bf16 MFMA-B-fragment order:
// frag(fk,fn): lane l, elem j  ->  W[fk*32 + (l>>4)*8 + j][fn*16 + (l&15)]
// offset(elems) = ((fk*nfn + fn)*64 + l)*8 + j
// ---------------------------------------------------------------------------
__global__ void prep_pack(const float* __restrict__ W1, const float* __restrict__ W2,
                          const float* __restrict__ W3, unsigned short* __restrict__ P) {
    int idx = blockIdx.x * 256 + threadIdx.x;
    const float* W; int N, base;
    if (idx < 131072)      { W = W1; N = 256; base = 0; }
    else if (idx < 196608) { W = W2; N = 256; base = 131072; }
    else if (idx < 229376) { W = W3; N = 128; base = 196608; }
    else return;
    int t = idx - base;
    int j = t & 7, l = (t >> 3) & 63, f = t >> 9;
    int nfn = N >> 4;
    int fk = f / nfn, fn = f - fk * nfn;
    int k = fk * 32 + ((l >> 4) << 3) + j;
    int c = fn * 16 + (l & 15);
    P[idx] = f2bf(W[k * N + c]);
}

// ---------------------------------------------------------------------------
// Main fused kernel. Block = 512 threads (8 waves as 2M x 4N), M_TILE = 64.
// Wave tile: 32 rows x 64 cols -> acc[2][4] = 32 regs.
// LDS: xs 2x8KB (dbuf 64x64 bf16 K-slice, swizzled) + hs 32KB = 48KB.
// ---------------------------------------------------------------------------
template <bool EXACT>
__global__ __launch_bounds__(512) void edge_mlp(
    const float* __restrict__ src, const float* __restrict__ dst,
    const float* __restrict__ ea,  const float* __restrict__ u,
    const int* __restrict__ batch, const unsigned short* __restrict__ Wp,
    const float* __restrict__ b1,  const float* __restrict__ b2,
    const float* __restrict__ b3,  const float* __restrict__ gamma,
    const float* __restrict__ beta, float* __restrict__ out, int E)
{
    __shared__ __align__(16) unsigned char xs[2][64 * 128];
    __shared__ __align__(16) unsigned char hs[64 * 512];

    const int tid  = threadIdx.x;
    const int lane = tid & 63;
    const int w    = tid >> 6;          // wave 0..7
    const int wm   = w >> 2;            // 0..1 (M half)
    const int wn   = w & 3;             // 0..3 (N quarter)
    const int l15  = lane & 15;
    const int lhi  = lane >> 4;         // 0..3
    const int m0   = blockIdx.x * 64;

    const unsigned short* W1p = Wp;
    const unsigned short* W2p = Wp + 131072;
    const unsigned short* W3p = Wp + 196608;

    const f32x4 zero4 = {0.f, 0.f, 0.f, 0.f};
    f32x4 acc[2][4];
    #pragma unroll
    for (int m = 0; m < 2; ++m)
        #pragma unroll
        for (int n = 0; n < 4; ++n) acc[m][n] = zero4;

    // ============================ layer 1 (K=512) ===========================
    // Double-buffered xs; per slice: issue next loads -> MFMA(cur) -> write
    // next buffer -> ONE barrier. Load latency hides under MFMA phase.
    f32x4 pf[2];
    const int ldr = tid >> 4;           // 0..31 (row within 32-row group)
    const int ldc = tid & 15;           // f32x4 column in 64-col slice
    {   // prologue: slice 0 (seg 0 = src, cols 0..63) -> xs[0]
        #pragma unroll
        for (int p = 0; p < 2; ++p) {
            int rg = m0 + p * 32 + ldr;
            if (!EXACT) rg = rg < E ? rg : E - 1;
            pf[p] = *reinterpret_cast<const f32x4*>(src + (size_t)rg * 128 + ldc * 4);
        }
        #pragma unroll
        for (int p = 0; p < 2; ++p) {
            int r = p * 32 + ldr;
            us4 h; h.x = f2bf(pf[p].x); h.y = f2bf(pf[p].y);
                   h.z = f2bf(pf[p].z); h.w = f2bf(pf[p].w);
            *reinterpret_cast<us4*>(&xs[0][r * 128 + ((ldc * 8) ^ ((r & 7) << 4))]) = h;
        }
        __syncthreads();
    }
    for (int ks = 0; ks < 8; ++ks) {
        const int cur = ks & 1;
        if (ks < 7) {   // issue next slice's global loads (consumed post-MFMA)
            const int ksn = ks + 1;
            const int seg = ksn >> 1;            // 0:src 1:dst 2:ea 3:u[batch]
            const int sc  = (ksn & 1) << 6;
            const float* bp = (seg == 0) ? src : (seg == 1) ? dst : ea;
            #pragma unroll
            for (int p = 0; p < 2; ++p) {
                int rg = m0 + p * 32 + ldr;
                if (!EXACT) rg = rg < E ? rg : E - 1;
                const float* gp = (seg == 3)
                    ? u  + (size_t)batch[rg] * 128 + sc + ldc * 4
                    : bp + (size_t)rg       * 128 + sc + ldc * 4;
                pf[p] = *reinterpret_cast<const f32x4*>(gp);
            }
        }
        #pragma unroll
        for (int kk = 0; kk < 2; ++kk) {       // two K=32 steps per slice
            const int klo = kk * 32 + lhi * 8;
            bf16x8 a[2], b[4];
            #pragma unroll
            for (int m = 0; m < 2; ++m) {
                int r = wm * 32 + m * 16 + l15;
                a[m] = *reinterpret_cast<const bf16x8*>(
                    &xs[cur][r * 128 + ((klo * 2) ^ ((r & 7) << 4))]);
            }
            const int fk = ks * 2 + kk;
            #pragma unroll
            for (int n = 0; n < 4; ++n) {
                int fn = wn * 4 + n;
                b[n] = *reinterpret_cast<const bf16x8*>(
                    W1p + (((fk * 16 + fn) << 6) + lane) * 8);
            }
            #pragma unroll
            for (int m = 0; m < 2; ++m)
                #pragma unroll
                for (int n = 0; n < 4; ++n)
                    acc[m][n] = __builtin_amdgcn_mfma_f32_16x16x32_bf16(
                        a[m], b[n], acc[m][n], 0, 0, 0);
        }
        if (ks < 7) {   // write prefetched slice into the other buffer
            #pragma unroll
            for (int p = 0; p < 2; ++p) {
                int r = p * 32 + ldr;
                us4 h; h.x = f2bf(pf[p].x); h.y = f2bf(pf[p].y);
                       h.z = f2bf(pf[p].z); h.w = f2bf(pf[p].w);
                *reinterpret_cast<us4*>(
                    &xs[cur ^ 1][r * 128 + ((ldc * 8) ^ ((r & 7) << 4))]) = h;
            }
        }
        __syncthreads();   // next buffer ready; cur fully consumed by all waves
    }
    // h1 = LReLU(acc + b1) -> hs (bf16, swizzled). hs first use: no barrier.
    #pragma unroll
    for (int n = 0; n < 4; ++n) {
        int col = wn * 64 + n * 16 + l15;
        float bias = b1[col];
        #pragma unroll
        for (int m = 0; m < 2; ++m)
            #pragma unroll
            for (int r = 0; r < 4; ++r) {
                int row = wm * 32 + m * 16 + lhi * 4 + r;
                float v = lrelu(acc[m][n][r] + bias);
                *reinterpret_cast<unsigned short*>(
                    &hs[row * 512 + ((col * 2) ^ ((row & 7) << 4))]) = f2bf(v);
            }
    }
    __syncthreads();

    // ============================ layer 2 (K=256) ===========================
    #pragma unroll
    for (int m = 0; m < 2; ++m)
        #pragma unroll
        for (int n = 0; n < 4; ++n) acc[m][n] = zero4;
    for (int kk = 0; kk < 8; ++kk) {
        const int k = kk * 32 + lhi * 8;
        bf16x8 a[2], b[4];
        #pragma unroll
        for (int m = 0; m < 2; ++m) {
            int r = wm * 32 + m * 16 + l15;
            a[m] = *reinterpret_cast<const bf16x8*>(
                &hs[r * 512 + ((k * 2) ^ ((r & 7) << 4))]);
        }
        #pragma unroll
        for (int n = 0; n < 4; ++n) {
            int fn = wn * 4 + n;
            b[n] = *reinterpret_cast<const bf16x8*>(
                W2p + (((kk * 16 + fn) << 6) + lane) * 8);
        }
        #pragma unroll
        for (int m = 0; m < 2; ++m)
            #pragma unroll
            for (int n = 0; n < 4; ++n)
                acc[m][n] = __builtin_amdgcn_mfma_f32_16x16x32_bf16(
                    a[m], b[n], acc[m][n], 0, 0, 0);
    }
    __syncthreads();   // all reads of h1 done before overwrite
    #pragma unroll
    for (int n = 0; n < 4; ++n) {
        int col = wn * 64 + n * 16 + l15;
        float bias = b2[col];
        #pragma unroll
        for (int m = 0; m < 2; ++m)
            #pragma unroll
            for (int r = 0; r < 4; ++r) {
                int row = wm * 32 + m * 16 + lhi * 4 + r;
                float v = lrelu(acc[m][n][r] + bias);
                *reinterpret_cast<unsigned short*>(
                    &hs[row * 512 + ((col * 2) ^ ((row & 7) << 4))]) = f2bf(v);
            }
    }
    __syncthreads();

    // ============================ layer 3 (K=256, N=128) ====================
    f32x4 acc3[2][2];
    #pragma unroll
    for (int m = 0; m < 2; ++m) { acc3[m][0] = zero4; acc3[m][1] = zero4; }
    for (int kk = 0; kk < 8; ++kk) {
        const int k = kk * 32 + lhi * 8;
        bf16x8 a[2], b[2];
        #pragma unroll
        for (int m = 0; m < 2; ++m) {
            int r = wm * 32 + m * 16 + l15;
            a[m] = *reinterpret_cast<const bf16x8*>(
                &hs[r * 512 + ((k * 2) ^ ((r & 7) << 4))]);
        }
        #pragma unroll
        for (int n = 0; n < 2; ++n) {
            int fn = wn * 2 + n;
            b[n] = *reinterpret_cast<const bf16x8*>(
                W3p + (((kk * 8 + fn) << 6) + lane) * 8);
        }
        #pragma unroll
        for (int m = 0; m < 2; ++m)
            #pragma unroll
            for (int n = 0; n < 2; ++n)
                acc3[m][n] = __builtin_amdgcn_mfma_f32_16x16x32_bf16(
                    a[m], b[n], acc3[m][n], 0, 0, 0);
    }
    __syncthreads();   // all reads of h2 done before f32 overwrite
    #pragma unroll
    for (int n = 0; n < 2; ++n) {
        int col = wn * 32 + n * 16 + l15;
        float bias = b3[col];
        #pragma unroll
        for (int m = 0; m < 2; ++m)
            #pragma unroll
            for (int r = 0; r < 4; ++r) {
                int row = wm * 32 + m * 16 + lhi * 4 + r;
                float v = lrelu(acc3[m][n][r] + bias);
                *reinterpret_cast<float*>(
                    &hs[row * 512 + ((col * 4) ^ ((row & 7) << 4))]) = v;
            }
    }
    __syncthreads();

    // ====================== LayerNorm(128) + store ==========================
    {
        const int row = tid >> 3;   // 0..63
        const int sub = tid & 7;    // 8 lanes per row (consecutive -> shfl_xor 1,2,4)
        f32x4 vv[4];
        float s = 0.f, s2 = 0.f;
        #pragma unroll
        for (int j = 0; j < 4; ++j) {
            int cb = sub * 16 + j * 4;
            f32x4 t = *reinterpret_cast<const f32x4*>(
                &hs[row * 512 + ((cb * 4) ^ ((row & 7) << 4))]);
            vv[j] = t;
            s  += t.x + t.y + t.z + t.w;
            s2 += t.x * t.x + t.y * t.y + t.z * t.z + t.w * t.w;
        }
        s  += __shfl_xor(s, 1);  s  += __shfl_xor(s, 2);  s  += __shfl_xor(s, 4);
        s2 += __shfl_xor(s2, 1); s2 += __shfl_xor(s2, 2); s2 += __shfl_xor(s2, 4);
        const float mean = s * (1.f / 128.f);
        const float var  = s2 * (1.f / 128.f) - mean * mean;
        const float rstd = rsqrtf(var + 1e-5f);
        const int rg = m0 + row;
        if (EXACT || rg < E) {
            float* op = out + (size_t)rg * 128;
            #pragma unroll
            for (int j = 0; j < 4; ++j) {
                int cb = sub * 16 + j * 4;
                f32x4 g  = *reinterpret_cast<const f32x4*>(gamma + cb);
                f32x4 be = *reinterpret_cast<const f32x4*>(beta + cb);
                f32x4 o;
                o.x = (vv[j].x - mean) * rstd * g.x + be.x;
                o.y = (vv[j].y - mean) * rstd * g.y + be.y;
                o.z = (vv[j].z - mean) * rstd * g.z + be.z;
                o.w = (vv[j].w - mean) * rstd * g.w + be.w;
                *reinterpret_cast<f32x4*>(op + cb) = o;
            }
        }
    }
}

extern "C" void kernel_launch(void* const* d_in, const int* in_sizes, int n_in,
                              void* d_out, int out_size, void* d_ws, size_t ws_size,
                              hipStream_t stream) {
    const float* src  = (const float*)d_in[0];
    const float* dst  = (const float*)d_in[1];
    const float* ea   = (const float*)d_in[2];
    const float* u    = (const float*)d_in[3];
    const int*   bat  = (const int*)d_in[4];
    const float* W1   = (const float*)d_in[5];
    const float* b1   = (const float*)d_in[6];
    const float* W2   = (const float*)d_in[7];
    const float* b2   = (const float*)d_in[8];
    const float* W3   = (const float*)d_in[9];
    const float* b3   = (const float*)d_in[10];
    const float* gam  = (const float*)d_in[11];
    const float* bet  = (const float*)d_in[12];
    float* out = (float*)d_out;
    unsigned short* Wp = (unsigned short*)d_ws;   // 458752 B used

    const int E = in_sizes[0] / 128;

    prep_pack<<<896, 256, 0, stream>>>(W1, W2, W3, Wp);
    const int nblk = (E + 63) / 64;
    if ((E & 63) == 0)
        edge_mlp<true><<<nblk, 512, 0, stream>>>(src, dst, ea, u, bat, Wp,
                                                 b1, b2, b3, gam, bet, out, E);
    else
        edge_mlp<false><<<nblk, 512, 0, stream>>>(src, dst, ea, u, bat, Wp,
                                                  b1, b2, b3, gam, bet, out, E);
}

// Round 7
// 405.659 us; speedup vs baseline: 1.3024x; 1.3024x over previous
//
#include <hip/hip_runtime.h>

// ---------------------------------------------------------------------------
// EdgeModel: out = LayerNorm(LReLU(LReLU(LReLU(X@W1+b1)@W2+b2)@W3+b3))
// X = concat[src, dest, edge_attr, u[batch]]  (E=400000, 512 features)
// R7: R5 geometry (M_TILE=32, 256thr, wave 32x64, acc[2][4]=32) but with
//     __launch_bounds__(256,3): cap 170 >> demand (~140) -> no spill
//     (R5's (256,4)=128 cap spilled), guaranteed 3 WGs/CU = 12 waves.
//     Plus register-level B-prefetch in all K-loops (b-frags for kk+1
//     issued before kk's MFMAs -> L2 latency hides under matrix pipe).
// ---------------------------------------------------------------------------

typedef short bf16x8 __attribute__((ext_vector_type(8)));   // 8 bf16 (guide §3)
typedef float f32x4 __attribute__((ext_vector_type(4)));
typedef unsigned short us4 __attribute__((ext_vector_type(4)));

__device__ __forceinline__ unsigned short f2bf(float f) {  // RNE f32->bf16
    union { float f; unsigned u; } v; v.f = f;
    return (unsigned short)((v.u + 0x7fffu + ((v.u >> 16) & 1u)) >> 16);
}
__device__ __forceinline__ float lrelu(float v) { return v >= 0.f ? v : 0.01f * v; }

// ---------------------------------------------------------------------------
// Pack W (K x N, row-major f32) into bf16 MFMA-B-fragment order:
// frag(fk,fn): lane l, elem j  ->  W[fk*32 + (l>>4)*8 + j][fn*16 + (l&15)]
// offset(elems) = ((fk*nfn + fn)*64 + l)*8 + j
// ---------------------------------------------------------------------------
__global__ void prep_pack(const float* __restrict__ W1, const float* __restrict__ W2,
                          const float* __restrict__ W3, unsigned short* __restrict__ P) {
    int idx = blockIdx.x * 256 + threadIdx.x;
    const float* W; int N, base;
    if (idx < 131072)      { W = W1; N = 256; base = 0; }
    else if (idx < 196608) { W = W2; N = 256; base = 131072; }
    else if (idx < 229376) { W = W3; N = 128; base = 196608; }
    else return;
    int t = idx - base;
    int j = t & 7, l = (t >> 3) & 63, f = t >> 9;
    int nfn = N >> 4;
    int fk = f / nfn, fn = f - fk * nfn;
    int k = fk * 32 + ((l >> 4) << 3) + j;
    int c = fn * 16 + (l & 15);
    P[idx] = f2bf(W[k * N + c]);
}

// ---------------------------------------------------------------------------
// Main fused kernel. Block = 256 threads (4 waves, 1M x 4N), M_TILE = 32.
// Wave tile: 32 rows x 64 cols -> acc[2][4] = 32 regs.
// LDS: xs 2x4KB (dbuf 32x64 bf16 K-slice, swizzled) + hs 16KB = 24KB.
// ---------------------------------------------------------------------------
template <bool EXACT>
__global__ __launch_bounds__(256, 3) void edge_mlp(
    const float* __restrict__ src, const float* __restrict__ dst,
    const float* __restrict__ ea,  const float* __restrict__ u,
    const int* __restrict__ batch, const unsigned short* __restrict__ Wp,
    const float* __restrict__ b1,  const float* __restrict__ b2,
    const float* __restrict__ b3,  const float* __restrict__ gamma,
    const float* __restrict__ beta, float* __restrict__ out, int E)
{
    __shared__ __align__(16) unsigned char xs[2][32 * 128];
    __shared__ __align__(16) unsigned char hs[32 * 512];

    const int tid  = threadIdx.x;
    const int lane = tid & 63;
    const int wn   = tid >> 6;          // wave 0..3 = N quarter
    const int l15  = lane & 15;
    const int lhi  = lane >> 4;         // 0..3
    const int m0   = blockIdx.x * 32;

    const unsigned short* W1p = Wp;
    const unsigned short* W2p = Wp + 131072;
    const unsigned short* W3p = Wp + 196608;

    const f32x4 zero4 = {0.f, 0.f, 0.f, 0.f};
    f32x4 acc[2][4];
    #pragma unroll
    for (int m = 0; m < 2; ++m)
        #pragma unroll
        for (int n = 0; n < 4; ++n) acc[m][n] = zero4;

    // ============================ layer 1 (K=512) ===========================
    // xs double-buffered; per slice: issue next global loads, load BOTH
    // kk-steps' b-frags up front (L2 latency overlaps 16 MFMAs), MFMA,
    // write prefetched slice, ONE barrier.
    f32x4 pf[2];
    const int ldr = tid >> 4;           // 0..15 (row within 16-row group)
    const int ldc = tid & 15;           // f32x4 column in 64-col slice
    {   // prologue: slice 0 (seg 0 = src, cols 0..63) -> xs[0]
        #pragma unroll
        for (int p = 0; p < 2; ++p) {
            int rg = m0 + p * 16 + ldr;
            if (!EXACT) rg = rg < E ? rg : E - 1;
            pf[p] = *reinterpret_cast<const f32x4*>(src + (size_t)rg * 128 + ldc * 4);
        }
        #pragma unroll
        for (int p = 0; p < 2; ++p) {
            int r = p * 16 + ldr;
            us4 h; h.x = f2bf(pf[p].x); h.y = f2bf(pf[p].y);
                   h.z = f2bf(pf[p].z); h.w = f2bf(pf[p].w);
            *reinterpret_cast<us4*>(&xs[0][r * 128 + ((ldc * 8) ^ ((r & 7) << 4))]) = h;
        }
        __syncthreads();
    }
    for (int ks = 0; ks < 8; ++ks) {
        const int cur = ks & 1;
        if (ks < 7) {   // issue next slice's global loads (consumed post-MFMA)
            const int ksn = ks + 1;
            const int seg = ksn >> 1;            // 0:src 1:dst 2:ea 3:u[batch]
            const int sc  = (ksn & 1) << 6;
            const float* bp = (seg == 0) ? src : (seg == 1) ? dst : ea;
            #pragma unroll
            for (int p = 0; p < 2; ++p) {
                int rg = m0 + p * 16 + ldr;
                if (!EXACT) rg = rg < E ? rg : E - 1;
                const float* gp = (seg == 3)
                    ? u  + (size_t)batch[rg] * 128 + sc + ldc * 4
                    : bp + (size_t)rg       * 128 + sc + ldc * 4;
                pf[p] = *reinterpret_cast<const f32x4*>(gp);
            }
        }
        // prefetch BOTH kk-steps' b-frags for this slice up front
        bf16x8 b0[4], b1v[4];
        #pragma unroll
        for (int n = 0; n < 4; ++n) {
            int fn = wn * 4 + n;
            b0[n]  = *reinterpret_cast<const bf16x8*>(
                W1p + ((((ks * 2 + 0) * 16 + fn) << 6) + lane) * 8);
            b1v[n] = *reinterpret_cast<const bf16x8*>(
                W1p + ((((ks * 2 + 1) * 16 + fn) << 6) + lane) * 8);
        }
        #pragma unroll
        for (int kk = 0; kk < 2; ++kk) {       // two K=32 steps per slice
            const int klo = kk * 32 + lhi * 8;
            bf16x8 a[2];
            #pragma unroll
            for (int m = 0; m < 2; ++m) {
                int r = m * 16 + l15;
                a[m] = *reinterpret_cast<const bf16x8*>(
                    &xs[cur][r * 128 + ((klo * 2) ^ ((r & 7) << 4))]);
            }
            #pragma unroll
            for (int m = 0; m < 2; ++m)
                #pragma unroll
                for (int n = 0; n < 4; ++n)
                    acc[m][n] = __builtin_amdgcn_mfma_f32_16x16x32_bf16(
                        a[m], kk == 0 ? b0[n] : b1v[n], acc[m][n], 0, 0, 0);
        }
        if (ks < 7) {   // write prefetched slice into the other buffer
            #pragma unroll
            for (int p = 0; p < 2; ++p) {
                int r = p * 16 + ldr;
                us4 h; h.x = f2bf(pf[p].x); h.y = f2bf(pf[p].y);
                       h.z = f2bf(pf[p].z); h.w = f2bf(pf[p].w);
                *reinterpret_cast<us4*>(
                    &xs[cur ^ 1][r * 128 + ((ldc * 8) ^ ((r & 7) << 4))]) = h;
            }
        }
        __syncthreads();   // next buffer ready; cur fully consumed by all waves
    }
    // h1 = LReLU(acc + b1) -> hs (bf16, swizzled). hs first use: no barrier.
    #pragma unroll
    for (int n = 0; n < 4; ++n) {
        int col = wn * 64 + n * 16 + l15;
        float bias = b1[col];
        #pragma unroll
        for (int m = 0; m < 2; ++m)
            #pragma unroll
            for (int r = 0; r < 4; ++r) {
                int row = m * 16 + lhi * 4 + r;
                float v = lrelu(acc[m][n][r] + bias);
                *reinterpret_cast<unsigned short*>(
                    &hs[row * 512 + ((col * 2) ^ ((row & 7) << 4))]) = f2bf(v);
            }
    }
    __syncthreads();

    // ============================ layer 2 (K=256) ===========================
    #pragma unroll
    for (int m = 0; m < 2; ++m)
        #pragma unroll
        for (int n = 0; n < 4; ++n) acc[m][n] = zero4;
    {   // software-pipelined: b for kk+1 issued before kk's MFMAs
        bf16x8 bc[4], bn[4];
        #pragma unroll
        for (int n = 0; n < 4; ++n)
            bc[n] = *reinterpret_cast<const bf16x8*>(
                W2p + (((0 * 16 + wn * 4 + n) << 6) + lane) * 8);
        #pragma unroll
        for (int kk = 0; kk < 8; ++kk) {
            if (kk < 7) {
                #pragma unroll
                for (int n = 0; n < 4; ++n)
                    bn[n] = *reinterpret_cast<const bf16x8*>(
                        W2p + ((((kk + 1) * 16 + wn * 4 + n) << 6) + lane) * 8);
            }
            const int k = kk * 32 + lhi * 8;
            bf16x8 a[2];
            #pragma unroll
            for (int m = 0; m < 2; ++m) {
                int r = m * 16 + l15;
                a[m] = *reinterpret_cast<const bf16x8*>(
                    &hs[r * 512 + ((k * 2) ^ ((r & 7) << 4))]);
            }
            #pragma unroll
            for (int m = 0; m < 2; ++m)
                #pragma unroll
                for (int n = 0; n < 4; ++n)
                    acc[m][n] = __builtin_amdgcn_mfma_f32_16x16x32_bf16(
                        a[m], bc[n], acc[m][n], 0, 0, 0);
            #pragma unroll
            for (int n = 0; n < 4; ++n) bc[n] = bn[n];
        }
    }
    __syncthreads();   // all reads of h1 done before overwrite
    #pragma unroll
    for (int n = 0; n < 4; ++n) {
        int col = wn * 64 + n * 16 + l15;
        float bias = b2[col];
        #pragma unroll
        for (int m = 0; m < 2; ++m)
            #pragma unroll
            for (int r = 0; r < 4; ++r) {
                int row = m * 16 + lhi * 4 + r;
                float v = lrelu(acc[m][n][r] + bias);
                *reinterpret_cast<unsigned short*>(
                    &hs[row * 512 + ((col * 2) ^ ((row & 7) << 4))]) = f2bf(v);
            }
    }
    __syncthreads();

    // ============================ layer 3 (K=256, N=128) ====================
    f32x4 acc3[2][2];
    #pragma unroll
    for (int m = 0; m < 2; ++m) { acc3[m][0] = zero4; acc3[m][1] = zero4; }
    {
        bf16x8 bc[2], bn[2];
        #pragma unroll
        for (int n = 0; n < 2; ++n)
            bc[n] = *reinterpret_cast<const bf16x8*>(
                W3p + (((0 * 8 + wn * 2 + n) << 6) + lane) * 8);
        #pragma unroll
        for (int kk = 0; kk < 8; ++kk) {
            if (kk < 7) {
                #pragma unroll
                for (int n = 0; n < 2; ++n)
                    bn[n] = *reinterpret_cast<const bf16x8*>(
                        W3p + ((((kk + 1) * 8 + wn * 2 + n) << 6) + lane) * 8);
            }
            const int k = kk * 32 + lhi * 8;
            bf16x8 a[2];
            #pragma unroll
            for (int m = 0; m < 2; ++m) {
                int r = m * 16 + l15;
                a[m] = *reinterpret_cast<const bf16x8*>(
                    &hs[r * 512 + ((k * 2) ^ ((r & 7) << 4))]);
            }
            #pragma unroll
            for (int m = 0; m < 2; ++m)
                #pragma unroll
                for (int n = 0; n < 2; ++n)
                    acc3[m][n] = __builtin_amdgcn_mfma_f32_16x16x32_bf16(
                        a[m], bc[n], acc3[m][n], 0, 0, 0);
            #pragma unroll
            for (int n = 0; n < 2; ++n) bc[n] = bn[n];
        }
    }
    __syncthreads();   // all reads of h2 done before f32 overwrite
    #pragma unroll
    for (int n = 0; n < 2; ++n) {
        int col = wn * 32 + n * 16 + l15;
        float bias = b3[col];
        #pragma unroll
        for (int m = 0; m < 2; ++m)
            #pragma unroll
            for (int r = 0; r < 4; ++r) {
                int row = m * 16 + lhi * 4 + r;
                float v = lrelu(acc3[m][n][r] + bias);
                *reinterpret_cast<float*>(
                    &hs[row * 512 + ((col * 4) ^ ((row & 7) << 4))]) = v;
            }
    }
    __syncthreads();

    // ====================== LayerNorm(128) + store ==========================
    {
        const int row = tid >> 3;   // 0..31
        const int sub = tid & 7;    // 8 lanes per row (consecutive -> shfl_xor 1,2,4)
        f32x4 vv[4];
        float s = 0.f, s2 = 0.f;
        #pragma unroll
        for (int j = 0; j < 4; ++j) {
            int cb = sub * 16 + j * 4;
            f32x4 t = *reinterpret_cast<const f32x4*>(
                &hs[row * 512 + ((cb * 4) ^ ((row & 7) << 4))]);
            vv[j] = t;
            s  += t.x + t.y + t.z + t.w;
            s2 += t.x * t.x + t.y * t.y + t.z * t.z + t.w * t.w;
        }
        s  += __shfl_xor(s, 1);  s  += __shfl_xor(s, 2);  s  += __shfl_xor(s, 4);
        s2 += __shfl_xor(s2, 1); s2 += __shfl_xor(s2, 2); s2 += __shfl_xor(s2, 4);
        const float mean = s * (1.f / 128.f);
        const float var  = s2 * (1.f / 128.f) - mean * mean;
        const float rstd = rsqrtf(var + 1e-5f);
        const int rg = m0 + row;
        if (EXACT || rg < E) {
            float* op = out + (size_t)rg * 128;
            #pragma unroll
            for (int j = 0; j < 4; ++j) {
                int cb = sub * 16 + j * 4;
                f32x4 g  = *reinterpret_cast<const f32x4*>(gamma + cb);
                f32x4 be = *reinterpret_cast<const f32x4*>(beta + cb);
                f32x4 o;
                o.x = (vv[j].x - mean) * rstd * g.x + be.x;
                o.y = (vv[j].y - mean) * rstd * g.y + be.y;
                o.z = (vv[j].z - mean) * rstd * g.z + be.z;
                o.w = (vv[j].w - mean) * rstd * g.w + be.w;
                *reinterpret_cast<f32x4*>(op + cb) = o;
            }
        }
    }
}

extern "C" void kernel_launch(void* const* d_in, const int* in_sizes, int n_in,
                              void* d_out, int out_size, void* d_ws, size_t ws_size,
                              hipStream_t stream) {
    const float* src  = (const float*)d_in[0];
    const float* dst  = (const float*)d_in[1];
    const float* ea   = (const float*)d_in[2];
    const float* u    = (const float*)d_in[3];
    const int*   bat  = (const int*)d_in[4];
    const float* W1   = (const float*)d_in[5];
    const float* b1   = (const float*)d_in[6];
    const float* W2   = (const float*)d_in[7];
    const float* b2   = (const float*)d_in[8];
    const float* W3   = (const float*)d_in[9];
    const float* b3   = (const float*)d_in[10];
    const float* gam  = (const float*)d_in[11];
    const float* bet  = (const float*)d_in[12];
    float* out = (float*)d_out;
    unsigned short* Wp = (unsigned short*)d_ws;   // 458752 B used

    const int E = in_sizes[0] / 128;

    prep_pack<<<896, 256, 0, stream>>>(W1, W2, W3, Wp);
    const int nblk = (E + 31) / 32;
    if ((E & 31) == 0)
        edge_mlp<true><<<nblk, 256, 0, stream>>>(src, dst, ea, u, bat, Wp,
                                                 b1, b2, b3, gam, bet, out, E);
    else
        edge_mlp<false><<<nblk, 256, 0, stream>>>(src, dst, ea, u, bat, Wp,
                                                  b1, b2, b3, gam, bet, out, E);
}

// Round 8
// 341.971 us; speedup vs baseline: 1.5449x; 1.1862x over previous
//
#include <hip/hip_runtime.h>

// ---------------------------------------------------------------------------
// EdgeModel: out = LayerNorm(LReLU(LReLU(LReLU(X@W1+b1)@W2+b2)@W3+b3))
// X = concat[src, dest, edge_attr, u[batch]]  (E=400000, 512 features)
// R8: R3 geometry (M_TILE=64, 256thr, 4 waves N-split, wave 64x64,
//     acc[4][4], no reg cap) + DEPTH-2 input prefetch: slice s+2 issued in
//     phase s, written in phase s+1 -> full MFMA phase between issue and
//     use (R3 exposed ~600cyc HBM latency every slice). batch[] gather
//     hoisted; per-slice upfront b-frags; pipelined b in L2/L3.
// ---------------------------------------------------------------------------

typedef short bf16x8 __attribute__((ext_vector_type(8)));   // 8 bf16 (guide §3)
typedef float f32x4 __attribute__((ext_vector_type(4)));
typedef unsigned short us4 __attribute__((ext_vector_type(4)));

__device__ __forceinline__ unsigned short f2bf(float f) {  // RNE f32->bf16
    union { float f; unsigned u; } v; v.f = f;
    return (unsigned short)((v.u + 0x7fffu + ((v.u >> 16) & 1u)) >> 16);
}
__device__ __forceinline__ float lrelu(float v) { return v >= 0.f ? v : 0.01f * v; }

// ---------------------------------------------------------------------------
// Pack W (K x N, row-major f32) into bf16 MFMA-B-fragment order:
// frag(fk,fn): lane l, elem j  ->  W[fk*32 + (l>>4)*8 + j][fn*16 + (l&15)]
// offset(elems) = ((fk*nfn + fn)*64 + l)*8 + j
// ---------------------------------------------------------------------------
__global__ void prep_pack(const float* __restrict__ W1, const float* __restrict__ W2,
                          const float* __restrict__ W3, unsigned short* __restrict__ P) {
    int idx = blockIdx.x * 256 + threadIdx.x;
    const float* W; int N, base;
    if (idx < 131072)      { W = W1; N = 256; base = 0; }
    else if (idx < 196608) { W = W2; N = 256; base = 131072; }
    else if (idx < 229376) { W = W3; N = 128; base = 196608; }
    else return;
    int t = idx - base;
    int j = t & 7, l = (t >> 3) & 63, f = t >> 9;
    int nfn = N >> 4;
    int fk = f / nfn, fn = f - fk * nfn;
    int k = fk * 32 + ((l >> 4) << 3) + j;
    int c = fn * 16 + (l & 15);
    P[idx] = f2bf(W[k * N + c]);
}

// ---------------------------------------------------------------------------
// Main fused kernel. Block = 256 threads (4 waves, 1M x 4N), M_TILE = 64.
// Wave tile: 64 rows x 64 cols -> acc[4][4] = 64 regs.
// LDS: xs 2x8KB (dbuf 64x64 bf16 K-slice, swizzled) + hs 32KB = 48KB.
// ---------------------------------------------------------------------------
template <bool EXACT>
__global__ __launch_bounds__(256) void edge_mlp(
    const float* __restrict__ src, const float* __restrict__ dst,
    const float* __restrict__ ea,  const float* __restrict__ u,
    const int* __restrict__ batch, const unsigned short* __restrict__ Wp,
    const float* __restrict__ b1,  const float* __restrict__ b2,
    const float* __restrict__ b3,  const float* __restrict__ gamma,
    const float* __restrict__ beta, float* __restrict__ out, int E)
{
    __shared__ __align__(16) unsigned char xs[2][64 * 128];
    __shared__ __align__(16) unsigned char hs[64 * 512];

    const int tid  = threadIdx.x;
    const int lane = tid & 63;
    const int wn   = tid >> 6;          // wave 0..3 = N quarter
    const int l15  = lane & 15;
    const int lhi  = lane >> 4;         // 0..3
    const int m0   = blockIdx.x * 64;
    const int ldr  = tid >> 4;          // 0..15: staging row within 16-row group
    const int ldc  = tid & 15;          // 0..15: f32x4 column in 64-col slice

    // Hoisted row indices + batch gather (kills dependent load chain in prefetch)
    int grow[4], gb[4];
    #pragma unroll
    for (int p = 0; p < 4; ++p) {
        int rg = m0 + p * 16 + ldr;     // rows 0..63 of the tile
        if (!EXACT) rg = rg < E ? rg : E - 1;
        grow[p] = rg;
        gb[p]   = batch[rg];
    }

    const unsigned short* W1p = Wp;
    const unsigned short* W2p = Wp + 131072;
    const unsigned short* W3p = Wp + 196608;

    const f32x4 zero4 = {0.f, 0.f, 0.f, 0.f};
    f32x4 acc[4][4];
    #pragma unroll
    for (int m = 0; m < 4; ++m)
        #pragma unroll
        for (int n = 0; n < 4; ++n) acc[m][n] = zero4;

    // Slice loader: ks in [0,8), seg = ks>>1 (0:src 1:dst 2:ea 3:u[batch])
    auto L1LOAD = [&](f32x4 (&pf)[4], int ks) {
        const int seg = ks >> 1;
        const int sc  = (ks & 1) << 6;
        #pragma unroll
        for (int p = 0; p < 4; ++p) {
            const float* gp;
            if (seg == 3) gp = u + (size_t)gb[p] * 128 + sc + ldc * 4;
            else {
                const float* bp = (seg == 0) ? src : (seg == 1) ? dst : ea;
                gp = bp + (size_t)grow[p] * 128 + sc + ldc * 4;
            }
            pf[p] = *reinterpret_cast<const f32x4*>(gp);
        }
    };
    auto L1WRITE = [&](unsigned char* buf, f32x4 (&pf)[4]) {
        #pragma unroll
        for (int p = 0; p < 4; ++p) {
            int r = p * 16 + ldr;       // 0..63
            us4 h; h.x = f2bf(pf[p].x); h.y = f2bf(pf[p].y);
                   h.z = f2bf(pf[p].z); h.w = f2bf(pf[p].w);
            *reinterpret_cast<us4*>(&buf[r * 128 + ((ldc * 8) ^ ((r & 7) << 4))]) = h;
        }
    };

    // ============================ layer 1 (K=512) ===========================
    // Depth-2 pipeline: phase ks reads xs[ks&1] (slice ks), writes slice ks+1
    // (regs->LDS), issues loads for slice ks+2. Full phase between issue+use.
    f32x4 pf0[4], pf1[4];
    L1LOAD(pf0, 0);
    L1WRITE(xs[0], pf0);                // exposed once (prologue only)
    L1LOAD(pf1, 1);
    __syncthreads();

    #pragma unroll
    for (int ks = 0; ks < 8; ++ks) {
        const int c = ks & 1;
        // issue slice ks+2 into the just-freed pf set (parity == c)
        if (ks + 2 < 8) { if (c == 0) L1LOAD(pf0, ks + 2); else L1LOAD(pf1, ks + 2); }
        // write slice ks+1 (loaded a full phase ago) into the other buffer
        if (ks + 1 < 8) { if (c == 0) L1WRITE(xs[1], pf1); else L1WRITE(xs[0], pf0); }
        // b-frags for both kk-steps of this slice, upfront
        bf16x8 bA[4], bB[4];
        #pragma unroll
        for (int n = 0; n < 4; ++n) {
            int fn = wn * 4 + n;
            bA[n] = *reinterpret_cast<const bf16x8*>(
                W1p + ((((2 * ks)     * 16 + fn) << 6) + lane) * 8);
            bB[n] = *reinterpret_cast<const bf16x8*>(
                W1p + ((((2 * ks + 1) * 16 + fn) << 6) + lane) * 8);
        }
        #pragma unroll
        for (int kk = 0; kk < 2; ++kk) {
            const int klo = kk * 32 + lhi * 8;
            bf16x8 a[4];
            #pragma unroll
            for (int m = 0; m < 4; ++m) {
                int r = m * 16 + l15;
                a[m] = *reinterpret_cast<const bf16x8*>(
                    &xs[c][r * 128 + ((klo * 2) ^ ((r & 7) << 4))]);
            }
            #pragma unroll
            for (int m = 0; m < 4; ++m)
                #pragma unroll
                for (int n = 0; n < 4; ++n)
                    acc[m][n] = __builtin_amdgcn_mfma_f32_16x16x32_bf16(
                        a[m], kk == 0 ? bA[n] : bB[n], acc[m][n], 0, 0, 0);
        }
        __syncthreads();   // xs[c^1] now ready for phase ks+1; xs[c] consumed
    }

    // h1 = LReLU(acc + b1) -> hs (bf16, swizzled). hs first use: no barrier.
    #pragma unroll
    for (int n = 0; n < 4; ++n) {
        int col = wn * 64 + n * 16 + l15;
        float bias = b1[col];
        #pragma unroll
        for (int m = 0; m < 4; ++m)
            #pragma unroll
            for (int r = 0; r < 4; ++r) {
                int row = m * 16 + lhi * 4 + r;
                float v = lrelu(acc[m][n][r] + bias);
                *reinterpret_cast<unsigned short*>(
                    &hs[row * 512 + ((col * 2) ^ ((row & 7) << 4))]) = f2bf(v);
            }
    }
    __syncthreads();

    // ============================ layer 2 (K=256) ===========================
    #pragma unroll
    for (int m = 0; m < 4; ++m)
        #pragma unroll
        for (int n = 0; n < 4; ++n) acc[m][n] = zero4;
    {   // pipelined: b for kk+1 issued before kk's MFMAs
        bf16x8 bc[4], bn[4];
        #pragma unroll
        for (int n = 0; n < 4; ++n)
            bc[n] = *reinterpret_cast<const bf16x8*>(
                W2p + (((wn * 4 + n) << 6) + lane) * 8);
        #pragma unroll
        for (int kk = 0; kk < 8; ++kk) {
            if (kk < 7) {
                #pragma unroll
                for (int n = 0; n < 4; ++n)
                    bn[n] = *reinterpret_cast<const bf16x8*>(
                        W2p + ((((kk + 1) * 16 + wn * 4 + n) << 6) + lane) * 8);
            }
            const int k = kk * 32 + lhi * 8;
            bf16x8 a[4];
            #pragma unroll
            for (int m = 0; m < 4; ++m) {
                int r = m * 16 + l15;
                a[m] = *reinterpret_cast<const bf16x8*>(
                    &hs[r * 512 + ((k * 2) ^ ((r & 7) << 4))]);
            }
            #pragma unroll
            for (int m = 0; m < 4; ++m)
                #pragma unroll
                for (int n = 0; n < 4; ++n)
                    acc[m][n] = __builtin_amdgcn_mfma_f32_16x16x32_bf16(
                        a[m], bc[n], acc[m][n], 0, 0, 0);
            #pragma unroll
            for (int n = 0; n < 4; ++n) bc[n] = bn[n];
        }
    }
    __syncthreads();   // all reads of h1 done before overwrite
    #pragma unroll
    for (int n = 0; n < 4; ++n) {
        int col = wn * 64 + n * 16 + l15;
        float bias = b2[col];
        #pragma unroll
        for (int m = 0; m < 4; ++m)
            #pragma unroll
            for (int r = 0; r < 4; ++r) {
                int row = m * 16 + lhi * 4 + r;
                float v = lrelu(acc[m][n][r] + bias);
                *reinterpret_cast<unsigned short*>(
                    &hs[row * 512 + ((col * 2) ^ ((row & 7) << 4))]) = f2bf(v);
            }
    }
    __syncthreads();

    // ============================ layer 3 (K=256, N=128) ====================
    f32x4 acc3[4][2];
    #pragma unroll
    for (int m = 0; m < 4; ++m) { acc3[m][0] = zero4; acc3[m][1] = zero4; }
    {
        bf16x8 bc[2], bn[2];
        #pragma unroll
        for (int n = 0; n < 2; ++n)
            bc[n] = *reinterpret_cast<const bf16x8*>(
                W3p + (((wn * 2 + n) << 6) + lane) * 8);
        #pragma unroll
        for (int kk = 0; kk < 8; ++kk) {
            if (kk < 7) {
                #pragma unroll
                for (int n = 0; n < 2; ++n)
                    bn[n] = *reinterpret_cast<const bf16x8*>(
                        W3p + ((((kk + 1) * 8 + wn * 2 + n) << 6) + lane) * 8);
            }
            const int k = kk * 32 + lhi * 8;
            bf16x8 a[4];
            #pragma unroll
            for (int m = 0; m < 4; ++m) {
                int r = m * 16 + l15;
                a[m] = *reinterpret_cast<const bf16x8*>(
                    &hs[r * 512 + ((k * 2) ^ ((r & 7) << 4))]);
            }
            #pragma unroll
            for (int m = 0; m < 4; ++m)
                #pragma unroll
                for (int n = 0; n < 2; ++n)
                    acc3[m][n] = __builtin_amdgcn_mfma_f32_16x16x32_bf16(
                        a[m], bc[n], acc3[m][n], 0, 0, 0);
            #pragma unroll
            for (int n = 0; n < 2; ++n) bc[n] = bn[n];
        }
    }
    __syncthreads();   // all reads of h2 done before f32 overwrite
    #pragma unroll
    for (int n = 0; n < 2; ++n) {
        int col = wn * 32 + n * 16 + l15;
        float bias = b3[col];
        #pragma unroll
        for (int m = 0; m < 4; ++m)
            #pragma unroll
            for (int r = 0; r < 4; ++r) {
                int row = m * 16 + lhi * 4 + r;
                float v = lrelu(acc3[m][n][r] + bias);
                *reinterpret_cast<float*>(
                    &hs[row * 512 + ((col * 4) ^ ((row & 7) << 4))]) = v;
            }
    }
    __syncthreads();

    // ====================== LayerNorm(128) + store ==========================
    {
        const int row = tid >> 2;   // 0..63
        const int sub = tid & 3;    // 4 lanes per row
        f32x4 vv[8];
        float s = 0.f, s2 = 0.f;
        #pragma unroll
        for (int j = 0; j < 8; ++j) {
            int cb = j * 16 + sub * 4;
            f32x4 t = *reinterpret_cast<const f32x4*>(
                &hs[row * 512 + ((cb * 4) ^ ((row & 7) << 4))]);
            vv[j] = t;
            s  += t.x + t.y + t.z + t.w;
            s2 += t.x * t.x + t.y * t.y + t.z * t.z + t.w * t.w;
        }
        s  += __shfl_xor(s, 1);  s  += __shfl_xor(s, 2);
        s2 += __shfl_xor(s2, 1); s2 += __shfl_xor(s2, 2);
        const float mean = s * (1.f / 128.f);
        const float var  = s2 * (1.f / 128.f) - mean * mean;
        const float rstd = rsqrtf(var + 1e-5f);
        const int rg = m0 + row;
        if (EXACT || rg < E) {
            float* op = out + (size_t)rg * 128;
            #pragma unroll
            for (int j = 0; j < 8; ++j) {
                int cb = j * 16 + sub * 4;
                f32x4 g  = *reinterpret_cast<const f32x4*>(gamma + cb);
                f32x4 be = *reinterpret_cast<const f32x4*>(beta + cb);
                f32x4 o;
                o.x = (vv[j].x - mean) * rstd * g.x + be.x;
                o.y = (vv[j].y - mean) * rstd * g.y + be.y;
                o.z = (vv[j].z - mean) * rstd * g.z + be.z;
                o.w = (vv[j].w - mean) * rstd * g.w + be.w;
                *reinterpret_cast<f32x4*>(op + cb) = o;
            }
        }
    }
}

extern "C" void kernel_launch(void* const* d_in, const int* in_sizes, int n_in,
                              void* d_out, int out_size, void* d_ws, size_t ws_size,
                              hipStream_t stream) {
    const float* src  = (const float*)d_in[0];
    const float* dst  = (const float*)d_in[1];
    const float* ea   = (const float*)d_in[2];
    const float* u    = (const float*)d_in[3];
    const int*   bat  = (const int*)d_in[4];
    const float* W1   = (const float*)d_in[5];
    const float* b1   = (const float*)d_in[6];
    const float* W2   = (const float*)d_in[7];
    const float* b2   = (const float*)d_in[8];
    const float* W3   = (const float*)d_in[9];
    const float* b3   = (const float*)d_in[10];
    const float* gam  = (const float*)d_in[11];
    const float* bet  = (const float*)d_in[12];
    float* out = (float*)d_out;
    unsigned short* Wp = (unsigned short*)d_ws;   // 458752 B used

    const int E = in_sizes[0] / 128;

    prep_pack<<<896, 256, 0, stream>>>(W1, W2, W3, Wp);
    const int nblk = (E + 63) / 64;
    if ((E & 63) == 0)
        edge_mlp<true><<<nblk, 256, 0, stream>>>(src, dst, ea, u, bat, Wp,
                                                 b1, b2, b3, gam, bet, out, E);
    else
        edge_mlp<false><<<nblk, 256, 0, stream>>>(src, dst, ea, u, bat, Wp,
                                                  b1, b2, b3, gam, bet, out, E);
}

// Round 9
// 307.565 us; speedup vs baseline: 1.7177x; 1.1119x over previous
//
#include <hip/hip_runtime.h>

// ---------------------------------------------------------------------------
// EdgeModel: out = LayerNorm(LReLU(LReLU(LReLU(X@W1+b1)@W2+b2)@W3+b3))
// X = concat[src, dest, edge_attr, u[batch]]  (E=400000, 512 features)
// R9: OPERAND SWAP. mfma(W_frag, x_frag, .) -> D[feat][edge]: lane holds 4
//     consecutive FEATURES of one edge -> h-epilogues become ds_write_b64/
//     b128 (was 64+64+32 scalar writes/thread) and packing becomes
//     v_cvt_pk_bf16_f32 (was 3-op bit-twiddle f2bf). Fragment layouts of
//     A(W) and B(x) are identical to what we already load: same prep_pack,
//     same LDS addresses -- only intrinsic arg order + epilogues change.
//     Keeps R8's depth-2 input prefetch + hoisted batch gather.
// ---------------------------------------------------------------------------

typedef short bf16x8 __attribute__((ext_vector_type(8)));   // 8 bf16 (guide §3)
typedef float f32x4 __attribute__((ext_vector_type(4)));
typedef unsigned int u32;
typedef unsigned int u32x2 __attribute__((ext_vector_type(2)));

__device__ __forceinline__ unsigned short f2bf(float f) {  // RNE f32->bf16
    union { float f; unsigned u; } v; v.f = f;
    return (unsigned short)((v.u + 0x7fffu + ((v.u >> 16) & 1u)) >> 16);
}
__device__ __forceinline__ u32 cvtpk(float lo, float hi) { // d={bf16(hi),bf16(lo)}
    u32 r;
    asm("v_cvt_pk_bf16_f32 %0, %1, %2" : "=v"(r) : "v"(lo), "v"(hi));
    return r;
}
__device__ __forceinline__ float lrelu(float v) { return v >= 0.f ? v : 0.01f * v; }

// ---------------------------------------------------------------------------
// Pack W (K x N, row-major f32) into bf16 MFMA fragment order (serves as the
// A-operand = W^T fragments after the swap; byte layout unchanged from R1):
// frag(fk,fn): lane l, elem j  ->  W[fk*32 + (l>>4)*8 + j][fn*16 + (l&15)]
// offset(elems) = ((fk*nfn + fn)*64 + l)*8 + j
// ---------------------------------------------------------------------------
__global__ void prep_pack(const float* __restrict__ W1, const float* __restrict__ W2,
                          const float* __restrict__ W3, unsigned short* __restrict__ P) {
    int idx = blockIdx.x * 256 + threadIdx.x;
    const float* W; int N, base;
    if (idx < 131072)      { W = W1; N = 256; base = 0; }
    else if (idx < 196608) { W = W2; N = 256; base = 131072; }
    else if (idx < 229376) { W = W3; N = 128; base = 196608; }
    else return;
    int t = idx - base;
    int j = t & 7, l = (t >> 3) & 63, f = t >> 9;
    int nfn = N >> 4;
    int fk = f / nfn, fn = f - fk * nfn;
    int k = fk * 32 + ((l >> 4) << 3) + j;
    int c = fn * 16 + (l & 15);
    P[idx] = f2bf(W[k * N + c]);
}

// ---------------------------------------------------------------------------
// Main fused kernel. Block = 256 threads (4 waves, feat-split), M_TILE = 64.
// Wave: 64 feats x 64 edges -> acc[4][4] (mf=feat-frag, nf=edge-frag).
// LDS: xs 2x8KB (dbuf 64x64 bf16 K-slice, swizzled) + hs 32KB = 48KB.
// ---------------------------------------------------------------------------
template <bool EXACT>
__global__ __launch_bounds__(256) void edge_mlp(
    const float* __restrict__ src, const float* __restrict__ dst,
    const float* __restrict__ ea,  const float* __restrict__ u,
    const int* __restrict__ batch, const unsigned short* __restrict__ Wp,
    const float* __restrict__ b1,  const float* __restrict__ b2,
    const float* __restrict__ b3,  const float* __restrict__ gamma,
    const float* __restrict__ beta, float* __restrict__ out, int E)
{
    __shared__ __align__(16) unsigned char xs[2][64 * 128];
    __shared__ __align__(16) unsigned char hs[64 * 512];

    const int tid  = threadIdx.x;
    const int lane = tid & 63;
    const int wn   = tid >> 6;          // wave 0..3 = feature quarter
    const int l15  = lane & 15;
    const int lhi  = lane >> 4;         // 0..3
    const int m0   = blockIdx.x * 64;
    const int ldr  = tid >> 4;          // 0..15: staging row within 16-row group
    const int ldc  = tid & 15;          // 0..15: f32x4 column in 64-col slice

    // Hoisted row indices + batch gather
    int grow[4], gb[4];
    #pragma unroll
    for (int p = 0; p < 4; ++p) {
        int rg = m0 + p * 16 + ldr;
        if (!EXACT) rg = rg < E ? rg : E - 1;
        grow[p] = rg;
        gb[p]   = batch[rg];
    }

    const unsigned short* W1p = Wp;
    const unsigned short* W2p = Wp + 131072;
    const unsigned short* W3p = Wp + 196608;

    const f32x4 zero4 = {0.f, 0.f, 0.f, 0.f};
    f32x4 acc[4][4];                    // [feat-frag][edge-frag]
    #pragma unroll
    for (int m = 0; m < 4; ++m)
        #pragma unroll
        for (int n = 0; n < 4; ++n) acc[m][n] = zero4;

    auto L1LOAD = [&](f32x4 (&pf)[4], int ks) {
        const int seg = ks >> 1;        // 0:src 1:dst 2:ea 3:u[batch]
        const int sc  = (ks & 1) << 6;
        #pragma unroll
        for (int p = 0; p < 4; ++p) {
            const float* gp;
            if (seg == 3) gp = u + (size_t)gb[p] * 128 + sc + ldc * 4;
            else {
                const float* bp = (seg == 0) ? src : (seg == 1) ? dst : ea;
                gp = bp + (size_t)grow[p] * 128 + sc + ldc * 4;
            }
            pf[p] = *reinterpret_cast<const f32x4*>(gp);
        }
    };
    auto L1WRITE = [&](unsigned char* buf, f32x4 (&pf)[4]) {
        #pragma unroll
        for (int p = 0; p < 4; ++p) {
            int r = p * 16 + ldr;
            u32x2 h; h.x = cvtpk(pf[p].x, pf[p].y); h.y = cvtpk(pf[p].z, pf[p].w);
            *reinterpret_cast<u32x2*>(&buf[r * 128 + ((ldc * 8) ^ ((r & 7) << 4))]) = h;
        }
    };

    // ============================ layer 1 (K=512) ===========================
    // Depth-2 pipeline: phase ks reads xs[ks&1], writes slice ks+1, issues ks+2.
    f32x4 pf0[4], pf1[4];
    L1LOAD(pf0, 0);
    L1WRITE(xs[0], pf0);
    L1LOAD(pf1, 1);
    __syncthreads();

    #pragma unroll
    for (int ks = 0; ks < 8; ++ks) {
        const int c = ks & 1;
        if (ks + 2 < 8) { if (c == 0) L1LOAD(pf0, ks + 2); else L1LOAD(pf1, ks + 2); }
        if (ks + 1 < 8) { if (c == 0) L1WRITE(xs[1], pf1); else L1WRITE(xs[0], pf0); }
        // W-frags (A operand) for both kk-steps, upfront
        bf16x8 wA[4], wB[4];
        #pragma unroll
        for (int m = 0; m < 4; ++m) {
            int fm = wn * 4 + m;
            wA[m] = *reinterpret_cast<const bf16x8*>(
                W1p + ((((2 * ks)     * 16 + fm) << 6) + lane) * 8);
            wB[m] = *reinterpret_cast<const bf16x8*>(
                W1p + ((((2 * ks + 1) * 16 + fm) << 6) + lane) * 8);
        }
        #pragma unroll
        for (int kk = 0; kk < 2; ++kk) {
            const int klo = kk * 32 + lhi * 8;
            bf16x8 xf[4];               // x-frags (B operand), edge-frags
            #pragma unroll
            for (int n = 0; n < 4; ++n) {
                int r = n * 16 + l15;
                xf[n] = *reinterpret_cast<const bf16x8*>(
                    &xs[c][r * 128 + ((klo * 2) ^ ((r & 7) << 4))]);
            }
            #pragma unroll
            for (int m = 0; m < 4; ++m)
                #pragma unroll
                for (int n = 0; n < 4; ++n)
                    acc[m][n] = __builtin_amdgcn_mfma_f32_16x16x32_bf16(
                        kk == 0 ? wA[m] : wB[m], xf[n], acc[m][n], 0, 0, 0);
        }
        __syncthreads();
    }

    // h1 = LReLU(acc + b1) -> hs. Lane holds feats f..f+3 of edge e: b64 write.
    #pragma unroll
    for (int m = 0; m < 4; ++m) {
        int f = wn * 64 + m * 16 + lhi * 4;
        f32x4 bb = *reinterpret_cast<const f32x4*>(b1 + f);
        #pragma unroll
        for (int n = 0; n < 4; ++n) {
            int e = n * 16 + l15;
            f32x4 v = acc[m][n];
            u32x2 h;
            h.x = cvtpk(lrelu(v[0] + bb.x), lrelu(v[1] + bb.y));
            h.y = cvtpk(lrelu(v[2] + bb.z), lrelu(v[3] + bb.w));
            *reinterpret_cast<u32x2*>(
                &hs[e * 512 + ((f * 2) ^ ((e & 7) << 4))]) = h;
        }
    }
    __syncthreads();

    // ============================ layer 2 (K=256) ===========================
    #pragma unroll
    for (int m = 0; m < 4; ++m)
        #pragma unroll
        for (int n = 0; n < 4; ++n) acc[m][n] = zero4;
    {   // pipelined W-frags: kk+1 issued before kk's MFMAs
        bf16x8 wc[4], wn_[4];
        #pragma unroll
        for (int m = 0; m < 4; ++m)
            wc[m] = *reinterpret_cast<const bf16x8*>(
                W2p + (((wn * 4 + m) << 6) + lane) * 8);
        #pragma unroll
        for (int kk = 0; kk < 8; ++kk) {
            if (kk < 7) {
                #pragma unroll
                for (int m = 0; m < 4; ++m)
                    wn_[m] = *reinterpret_cast<const bf16x8*>(
                        W2p + ((((kk + 1) * 16 + wn * 4 + m) << 6) + lane) * 8);
            }
            const int k = kk * 32 + lhi * 8;
            bf16x8 xf[4];
            #pragma unroll
            for (int n = 0; n < 4; ++n) {
                int r = n * 16 + l15;
                xf[n] = *reinterpret_cast<const bf16x8*>(
                    &hs[r * 512 + ((k * 2) ^ ((r & 7) << 4))]);
            }
            #pragma unroll
            for (int m = 0; m < 4; ++m)
                #pragma unroll
                for (int n = 0; n < 4; ++n)
                    acc[m][n] = __builtin_amdgcn_mfma_f32_16x16x32_bf16(
                        wc[m], xf[n], acc[m][n], 0, 0, 0);
            #pragma unroll
            for (int m = 0; m < 4; ++m) wc[m] = wn_[m];
        }
    }
    __syncthreads();   // all reads of h1 done before overwrite
    #pragma unroll
    for (int m = 0; m < 4; ++m) {
        int f = wn * 64 + m * 16 + lhi * 4;
        f32x4 bb = *reinterpret_cast<const f32x4*>(b2 + f);
        #pragma unroll
        for (int n = 0; n < 4; ++n) {
            int e = n * 16 + l15;
            f32x4 v = acc[m][n];
            u32x2 h;
            h.x = cvtpk(lrelu(v[0] + bb.x), lrelu(v[1] + bb.y));
            h.y = cvtpk(lrelu(v[2] + bb.z), lrelu(v[3] + bb.w));
            *reinterpret_cast<u32x2*>(
                &hs[e * 512 + ((f * 2) ^ ((e & 7) << 4))]) = h;
        }
    }
    __syncthreads();

    // ============================ layer 3 (K=256, N=128 feats) ==============
    f32x4 acc3[2][4];                   // [feat-frag (2)][edge-frag (4)]
    #pragma unroll
    for (int m = 0; m < 2; ++m)
        #pragma unroll
        for (int n = 0; n < 4; ++n) acc3[m][n] = zero4;
    {
        bf16x8 wc[2], wn_[2];
        #pragma unroll
        for (int m = 0; m < 2; ++m)
            wc[m] = *reinterpret_cast<const bf16x8*>(
                W3p + (((wn * 2 + m) << 6) + lane) * 8);
        #pragma unroll
        for (int kk = 0; kk < 8; ++kk) {
            if (kk < 7) {
                #pragma unroll
                for (int m = 0; m < 2; ++m)
                    wn_[m] = *reinterpret_cast<const bf16x8*>(
                        W3p + ((((kk + 1) * 8 + wn * 2 + m) << 6) + lane) * 8);
            }
            const int k = kk * 32 + lhi * 8;
            bf16x8 xf[4];
            #pragma unroll
            for (int n = 0; n < 4; ++n) {
                int r = n * 16 + l15;
                xf[n] = *reinterpret_cast<const bf16x8*>(
                    &hs[r * 512 + ((k * 2) ^ ((r & 7) << 4))]);
            }
            #pragma unroll
            for (int m = 0; m < 2; ++m)
                #pragma unroll
                for (int n = 0; n < 4; ++n)
                    acc3[m][n] = __builtin_amdgcn_mfma_f32_16x16x32_bf16(
                        wc[m], xf[n], acc3[m][n], 0, 0, 0);
            #pragma unroll
            for (int m = 0; m < 2; ++m) wc[m] = wn_[m];
        }
    }
    __syncthreads();   // all reads of h2 done before f32 overwrite
    #pragma unroll
    for (int m = 0; m < 2; ++m) {
        int f = wn * 32 + m * 16 + lhi * 4;
        f32x4 bb = *reinterpret_cast<const f32x4*>(b3 + f);
        #pragma unroll
        for (int n = 0; n < 4; ++n) {
            int e = n * 16 + l15;
            f32x4 v = acc3[m][n];
            f32x4 o;
            o.x = lrelu(v[0] + bb.x); o.y = lrelu(v[1] + bb.y);
            o.z = lrelu(v[2] + bb.z); o.w = lrelu(v[3] + bb.w);
            *reinterpret_cast<f32x4*>(
                &hs[e * 512 + ((f * 4) ^ ((e & 7) << 4))]) = o;
        }
    }
    __syncthreads();

    // ====================== LayerNorm(128) + store ==========================
    {
        const int row = tid >> 2;   // 0..63
        const int sub = tid & 3;    // 4 lanes per row
        f32x4 vv[8];
        float s = 0.f, s2 = 0.f;
        #pragma unroll
        for (int j = 0; j < 8; ++j) {
            int cb = j * 16 + sub * 4;
            f32x4 t = *reinterpret_cast<const f32x4*>(
                &hs[row * 512 + ((cb * 4) ^ ((row & 7) << 4))]);
            vv[j] = t;
            s  += t.x + t.y + t.z + t.w;
            s2 += t.x * t.x + t.y * t.y + t.z * t.z + t.w * t.w;
        }
        s  += __shfl_xor(s, 1);  s  += __shfl_xor(s, 2);
        s2 += __shfl_xor(s2, 1); s2 += __shfl_xor(s2, 2);
        const float mean = s * (1.f / 128.f);
        const float var  = s2 * (1.f / 128.f) - mean * mean;
        const float rstd = rsqrtf(var + 1e-5f);
        const int rg = m0 + row;
        if (EXACT || rg < E) {
            float* op = out + (size_t)rg * 128;
            #pragma unroll
            for (int j = 0; j < 8; ++j) {
                int cb = j * 16 + sub * 4;
                f32x4 g  = *reinterpret_cast<const f32x4*>(gamma + cb);
                f32x4 be = *reinterpret_cast<const f32x4*>(beta + cb);
                f32x4 o;
                o.x = (vv[j].x - mean) * rstd * g.x + be.x;
                o.y = (vv[j].y - mean) * rstd * g.y + be.y;
                o.z = (vv[j].z - mean) * rstd * g.z + be.z;
                o.w = (vv[j].w - mean) * rstd * g.w + be.w;
                *reinterpret_cast<f32x4*>(op + cb) = o;
            }
        }
    }
}

extern "C" void kernel_launch(void* const* d_in, const int* in_sizes, int n_in,
                              void* d_out, int out_size, void* d_ws, size_t ws_size,
                              hipStream_t stream) {
    const float* src  = (const float*)d_in[0];
    const float* dst  = (const float*)d_in[1];
    const float* ea   = (const float*)d_in[2];
    const float* u    = (const float*)d_in[3];
    const int*   bat  = (const int*)d_in[4];
    const float* W1   = (const float*)d_in[5];
    const float* b1   = (const float*)d_in[6];
    const float* W2   = (const float*)d_in[7];
    const float* b2   = (const float*)d_in[8];
    const float* W3   = (const float*)d_in[9];
    const float* b3   = (const float*)d_in[10];
    const float* gam  = (const float*)d_in[11];
    const float* bet  = (const float*)d_in[12];
    float* out = (float*)d_out;
    unsigned short* Wp = (unsigned short*)d_ws;   // 458752 B used

    const int E = in_sizes[0] / 128;

    prep_pack<<<896, 256, 0, stream>>>(W1, W2, W3, Wp);
    const int nblk = (E + 63) / 64;
    if ((E & 63) == 0)
        edge_mlp<true><<<nblk, 256, 0, stream>>>(src, dst, ea, u, bat, Wp,
                                                 b1, b2, b3, gam, bet, out, E);
    else
        edge_mlp<false><<<nblk, 256, 0, stream>>>(src, dst, ea, u, bat, Wp,
                                                  b1, b2, b3, gam, bet, out, E);
}

// Round 10
// 291.011 us; speedup vs baseline: 1.8154x; 1.0569x over previous
//
#include <hip/hip_runtime.h>

// ---------------------------------------------------------------------------
// EdgeModel: out = LayerNorm(LReLU(LReLU(LReLU(X@W1+b1)@W2+b2)@W3+b3))
// X = concat[src, dest, edge_attr, u[batch]]  (E=400000, 512 features)
// R10: fewer/fatter phases. L1 = 4 phases of K=128 (one segment each, 64
//      MFMA/barrier, was 8 phases x 16 MFMA). h2 -> dead xs region, h3->hs
//      only after pre-L3 barrier: 14 -> 8 barriers total. s_setprio(1/0)
//      around all MFMA clusters (T5: independent-block waves arbitrage).
//      Keeps R9 operand swap (D[feat][edge], vector epilogues, cvt_pk) and
//      R8 depth-2 input prefetch + hoisted batch gather.
// ---------------------------------------------------------------------------

typedef short bf16x8 __attribute__((ext_vector_type(8)));   // 8 bf16 (guide §3)
typedef float f32x4 __attribute__((ext_vector_type(4)));
typedef unsigned int u32;
typedef unsigned int u32x2 __attribute__((ext_vector_type(2)));

__device__ __forceinline__ unsigned short f2bf(float f) {  // RNE f32->bf16
    union { float f; unsigned u; } v; v.f = f;
    return (unsigned short)((v.u + 0x7fffu + ((v.u >> 16) & 1u)) >> 16);
}
__device__ __forceinline__ u32 cvtpk(float lo, float hi) { // d={bf16(hi),bf16(lo)}
    u32 r;
    asm("v_cvt_pk_bf16_f32 %0, %1, %2" : "=v"(r) : "v"(lo), "v"(hi));
    return r;
}
__device__ __forceinline__ float lrelu(float v) { return v >= 0.f ? v : 0.01f * v; }

// ---------------------------------------------------------------------------
// Pack W (K x N, row-major f32) into bf16 MFMA fragment order (A operand):
// frag(fk,fn): lane l, elem j  ->  W[fk*32 + (l>>4)*8 + j][fn*16 + (l&15)]
// offset(elems) = ((fk*nfn + fn)*64 + l)*8 + j
// ---------------------------------------------------------------------------
__global__ void prep_pack(const float* __restrict__ W1, const float* __restrict__ W2,
                          const float* __restrict__ W3, unsigned short* __restrict__ P) {
    int idx = blockIdx.x * 256 + threadIdx.x;
    const float* W; int N, base;
    if (idx < 131072)      { W = W1; N = 256; base = 0; }
    else if (idx < 196608) { W = W2; N = 256; base = 131072; }
    else if (idx < 229376) { W = W3; N = 128; base = 196608; }
    else return;
    int t = idx - base;
    int j = t & 7, l = (t >> 3) & 63, f = t >> 9;
    int nfn = N >> 4;
    int fk = f / nfn, fn = f - fk * nfn;
    int k = fk * 32 + ((l >> 4) << 3) + j;
    int c = fn * 16 + (l & 15);
    P[idx] = f2bf(W[k * N + c]);
}

// ---------------------------------------------------------------------------
// Main fused kernel. Block = 256 threads (4 waves, feat-split), M_TILE = 64.
// Wave: 64 feats x 64 edges. acc[4][4] (feat-frag x edge-frag), D[feat][edge].
// LDS: xs 2x16KB (dbuf 64x128 bf16 K-slice, swizzled; reused as h2 after L1)
//    + hs 32KB (h1 bf16 -> h3 f32) = 64KB -> 2 blocks/CU.
// ---------------------------------------------------------------------------
template <bool EXACT>
__global__ __launch_bounds__(256) void edge_mlp(
    const float* __restrict__ src, const float* __restrict__ dst,
    const float* __restrict__ ea,  const float* __restrict__ u,
    const int* __restrict__ batch, const unsigned short* __restrict__ Wp,
    const float* __restrict__ b1,  const float* __restrict__ b2,
    const float* __restrict__ b3,  const float* __restrict__ gamma,
    const float* __restrict__ beta, float* __restrict__ out, int E)
{
    __shared__ __align__(16) unsigned char xs[2][64 * 256];  // 2x16KB
    __shared__ __align__(16) unsigned char hs[64 * 512];     // 32KB

    const int tid  = threadIdx.x;
    const int lane = tid & 63;
    const int wn   = tid >> 6;          // wave 0..3 = feature quarter
    const int l15  = lane & 15;
    const int lhi  = lane >> 4;         // 0..3
    const int m0   = blockIdx.x * 64;
    const int ldr8 = tid >> 5;          // 0..7: staging row within 8-row group
    const int ldc5 = tid & 31;          // 0..31: f32x4 column in 128-col slice

    // Hoisted row indices + batch gather (one per 8-row group)
    int grow[8], gb[8];
    #pragma unroll
    for (int p = 0; p < 8; ++p) {
        int rg = m0 + p * 8 + ldr8;
        if (!EXACT) rg = rg < E ? rg : E - 1;
        grow[p] = rg;
        gb[p]   = batch[rg];
    }

    const unsigned short* W1p = Wp;
    const unsigned short* W2p = Wp + 131072;
    const unsigned short* W3p = Wp + 196608;

    const f32x4 zero4 = {0.f, 0.f, 0.f, 0.f};
    f32x4 acc[4][4];                    // [feat-frag][edge-frag]
    #pragma unroll
    for (int m = 0; m < 4; ++m)
        #pragma unroll
        for (int n = 0; n < 4; ++n) acc[m][n] = zero4;

    // Load one full 128-K segment (seg: 0:src 1:dst 2:ea 3:u[batch])
    auto L1LOAD = [&](f32x4 (&pf)[8], int seg) {
        #pragma unroll
        for (int p = 0; p < 8; ++p) {
            const float* gp;
            if (seg == 3) gp = u + (size_t)gb[p] * 128 + ldc5 * 4;
            else {
                const float* bp = (seg == 0) ? src : (seg == 1) ? dst : ea;
                gp = bp + (size_t)grow[p] * 128 + ldc5 * 4;
            }
            pf[p] = *reinterpret_cast<const f32x4*>(gp);
        }
    };
    auto L1WRITE = [&](unsigned char* buf, f32x4 (&pf)[8]) {
        #pragma unroll
        for (int p = 0; p < 8; ++p) {
            int r = p * 8 + ldr8;
            u32x2 h; h.x = cvtpk(pf[p].x, pf[p].y); h.y = cvtpk(pf[p].z, pf[p].w);
            *reinterpret_cast<u32x2*>(
                &buf[r * 256 + ((ldc5 * 8) ^ ((r & 7) << 4))]) = h;
        }
    };

    // ============================ layer 1 (K=512) ===========================
    // 4 phases of K=128; depth-2: phase p reads xs[p&1] (seg p), writes seg
    // p+1 (loaded a full phase ago), issues loads for seg p+2.
    f32x4 pf0[8], pf1[8];
    L1LOAD(pf0, 0);
    L1WRITE(xs[0], pf0);
    L1LOAD(pf1, 1);
    __syncthreads();

    #pragma unroll
    for (int p = 0; p < 4; ++p) {
        const int c = p & 1;
        if (p + 2 < 4) { if (c == 0) L1LOAD(pf0, p + 2); else L1LOAD(pf1, p + 2); }
        if (p + 1 < 4) { if (c == 0) L1WRITE(xs[1], pf1); else L1WRITE(xs[0], pf0); }
        #pragma unroll
        for (int h = 0; h < 2; ++h) {   // two K=64 halves; W-frags 2 kk upfront
            bf16x8 wA[4], wB[4];
            const int fkA = p * 4 + h * 2, fkB = fkA + 1;
            #pragma unroll
            for (int m = 0; m < 4; ++m) {
                int fm = wn * 4 + m;
                wA[m] = *reinterpret_cast<const bf16x8*>(
                    W1p + (((fkA * 16 + fm) << 6) + lane) * 8);
                wB[m] = *reinterpret_cast<const bf16x8*>(
                    W1p + (((fkB * 16 + fm) << 6) + lane) * 8);
            }
            #pragma unroll
            for (int kk = 0; kk < 2; ++kk) {
                const int klo = (h * 2 + kk) * 32 + lhi * 8;
                bf16x8 xf[4];
                #pragma unroll
                for (int n = 0; n < 4; ++n) {
                    int r = n * 16 + l15;
                    xf[n] = *reinterpret_cast<const bf16x8*>(
                        &xs[c][r * 256 + ((klo * 2) ^ ((r & 7) << 4))]);
                }
                __builtin_amdgcn_s_setprio(1);
                #pragma unroll
                for (int m = 0; m < 4; ++m)
                    #pragma unroll
                    for (int n = 0; n < 4; ++n)
                        acc[m][n] = __builtin_amdgcn_mfma_f32_16x16x32_bf16(
                            kk == 0 ? wA[m] : wB[m], xf[n], acc[m][n], 0, 0, 0);
                __builtin_amdgcn_s_setprio(0);
            }
        }
        __syncthreads();
    }

    // h1 = LReLU(acc + b1) -> hs. Lane holds 4 consecutive feats of one edge.
    #pragma unroll
    for (int m = 0; m < 4; ++m) {
        int f = wn * 64 + m * 16 + lhi * 4;
        f32x4 bb = *reinterpret_cast<const f32x4*>(b1 + f);
        #pragma unroll
        for (int n = 0; n < 4; ++n) {
            int e = n * 16 + l15;
            f32x4 v = acc[m][n];
            u32x2 h;
            h.x = cvtpk(lrelu(v[0] + bb.x), lrelu(v[1] + bb.y));
            h.y = cvtpk(lrelu(v[2] + bb.z), lrelu(v[3] + bb.w));
            *reinterpret_cast<u32x2*>(
                &hs[e * 512 + ((f * 2) ^ ((e & 7) << 4))]) = h;
        }
    }
    __syncthreads();

    // ============================ layer 2 (K=256) ===========================
    // reads h1 (hs), writes h2 into the DEAD xs region (no overwrite barrier).
    unsigned char* h2s = xs[0];          // 32KB contiguous
    #pragma unroll
    for (int m = 0; m < 4; ++m)
        #pragma unroll
        for (int n = 0; n < 4; ++n) acc[m][n] = zero4;
    {   // pipelined W-frags: kk+1 issued before kk's MFMAs
        bf16x8 wc[4], wn_[4];
        #pragma unroll
        for (int m = 0; m < 4; ++m)
            wc[m] = *reinterpret_cast<const bf16x8*>(
                W2p + (((wn * 4 + m) << 6) + lane) * 8);
        #pragma unroll
        for (int kk = 0; kk < 8; ++kk) {
            if (kk < 7) {
                #pragma unroll
                for (int m = 0; m < 4; ++m)
                    wn_[m] = *reinterpret_cast<const bf16x8*>(
                        W2p + ((((kk + 1) * 16 + wn * 4 + m) << 6) + lane) * 8);
            }
            const int k = kk * 32 + lhi * 8;
            bf16x8 xf[4];
            #pragma unroll
            for (int n = 0; n < 4; ++n) {
                int r = n * 16 + l15;
                xf[n] = *reinterpret_cast<const bf16x8*>(
                    &hs[r * 512 + ((k * 2) ^ ((r & 7) << 4))]);
            }
            __builtin_amdgcn_s_setprio(1);
            #pragma unroll
            for (int m = 0; m < 4; ++m)
                #pragma unroll
                for (int n = 0; n < 4; ++n)
                    acc[m][n] = __builtin_amdgcn_mfma_f32_16x16x32_bf16(
                        wc[m], xf[n], acc[m][n], 0, 0, 0);
            __builtin_amdgcn_s_setprio(0);
            #pragma unroll
            for (int m = 0; m < 4; ++m) wc[m] = wn_[m];
        }
    }
    // h2 epilogue -> h2s (disjoint from hs; xs dead): no pre-barrier needed.
    #pragma unroll
    for (int m = 0; m < 4; ++m) {
        int f = wn * 64 + m * 16 + lhi * 4;
        f32x4 bb = *reinterpret_cast<const f32x4*>(b2 + f);
        #pragma unroll
        for (int n = 0; n < 4; ++n) {
            int e = n * 16 + l15;
            f32x4 v = acc[m][n];
            u32x2 h;
            h.x = cvtpk(lrelu(v[0] + bb.x), lrelu(v[1] + bb.y));
            h.y = cvtpk(lrelu(v[2] + bb.z), lrelu(v[3] + bb.w));
            *reinterpret_cast<u32x2*>(
                &h2s[e * 512 + ((f * 2) ^ ((e & 7) << 4))]) = h;
        }
    }
    __syncthreads();   // h2 visible; also: all waves done READING h1 (hs)

    // ============================ layer 3 (K=256, N=128 feats) ==============
    f32x4 acc3[2][4];
    #pragma unroll
    for (int m = 0; m < 2; ++m)
        #pragma unroll
        for (int n = 0; n < 4; ++n) acc3[m][n] = zero4;
    {
        bf16x8 wc[2], wn_[2];
        #pragma unroll
        for (int m = 0; m < 2; ++m)
            wc[m] = *reinterpret_cast<const bf16x8*>(
                W3p + (((wn * 2 + m) << 6) + lane) * 8);
        #pragma unroll
        for (int kk = 0; kk < 8; ++kk) {
            if (kk < 7) {
                #pragma unroll
                for (int m = 0; m < 2; ++m)
                    wn_[m] = *reinterpret_cast<const bf16x8*>(
                        W3p + ((((kk + 1) * 8 + wn * 2 + m) << 6) + lane) * 8);
            }
            const int k = kk * 32 + lhi * 8;
            bf16x8 xf[4];
            #pragma unroll
            for (int n = 0; n < 4; ++n) {
                int r = n * 16 + l15;
                xf[n] = *reinterpret_cast<const bf16x8*>(
                    &h2s[r * 512 + ((k * 2) ^ ((r & 7) << 4))]);
            }
            __builtin_amdgcn_s_setprio(1);
            #pragma unroll
            for (int m = 0; m < 2; ++m)
                #pragma unroll
                for (int n = 0; n < 4; ++n)
                    acc3[m][n] = __builtin_amdgcn_mfma_f32_16x16x32_bf16(
                        wc[m], xf[n], acc3[m][n], 0, 0, 0);
            __builtin_amdgcn_s_setprio(0);
            #pragma unroll
            for (int m = 0; m < 2; ++m) wc[m] = wn_[m];
        }
    }
    // h3 epilogue writes f32 into hs: all h1 reads finished at pre-L3 barrier.
    #pragma unroll
    for (int m = 0; m < 2; ++m) {
        int f = wn * 32 + m * 16 + lhi * 4;
        f32x4 bb = *reinterpret_cast<const f32x4*>(b3 + f);
        #pragma unroll
        for (int n = 0; n < 4; ++n) {
            int e = n * 16 + l15;
            f32x4 v = acc3[m][n];
            f32x4 o;
            o.x = lrelu(v[0] + bb.x); o.y = lrelu(v[1] + bb.y);
            o.z = lrelu(v[2] + bb.z); o.w = lrelu(v[3] + bb.w);
            *reinterpret_cast<f32x4*>(
                &hs[e * 512 + ((f * 4) ^ ((e & 7) << 4))]) = o;
        }
    }
    __syncthreads();

    // ====================== LayerNorm(128) + store ==========================
    {
        const int row = tid >> 2;   // 0..63
        const int sub = tid & 3;    // 4 lanes per row
        f32x4 vv[8];
        float s = 0.f, s2 = 0.f;
        #pragma unroll
        for (int j = 0; j < 8; ++j) {
            int cb = j * 16 + sub * 4;
            f32x4 t = *reinterpret_cast<const f32x4*>(
                &hs[row * 512 + ((cb * 4) ^ ((row & 7) << 4))]);
            vv[j] = t;
            s  += t.x + t.y + t.z + t.w;
            s2 += t.x * t.x + t.y * t.y + t.z * t.z + t.w * t.w;
        }
        s  += __shfl_xor(s, 1);  s  += __shfl_xor(s, 2);
        s2 += __shfl_xor(s2, 1); s2 += __shfl_xor(s2, 2);
        const float mean = s * (1.f / 128.f);
        const float var  = s2 * (1.f / 128.f) - mean * mean;
        const float rstd = rsqrtf(var + 1e-5f);
        const int rg = m0 + row;
        if (EXACT || rg < E) {
            float* op = out + (size_t)rg * 128;
            #pragma unroll
            for (int j = 0; j < 8; ++j) {
                int cb = j * 16 + sub * 4;
                f32x4 g  = *reinterpret_cast<const f32x4*>(gamma + cb);
                f32x4 be = *reinterpret_cast<const f32x4*>(beta + cb);
                f32x4 o;
                o.x = (vv[j].x - mean) * rstd * g.x + be.x;
                o.y = (vv[j].y - mean) * rstd * g.y + be.y;
                o.z = (vv[j].z - mean) * rstd * g.z + be.z;
                o.w = (vv[j].w - mean) * rstd * g.w + be.w;
                *reinterpret_cast<f32x4*>(op + cb) = o;
            }
        }
    }
}

extern "C" void kernel_launch(void* const* d_in, const int* in_sizes, int n_in,
                              void* d_out, int out_size, void* d_ws, size_t ws_size,
                              hipStream_t stream) {
    const float* src  = (const float*)d_in[0];
    const float* dst  = (const float*)d_in[1];
    const float* ea   = (const float*)d_in[2];
    const float* u    = (const float*)d_in[3];
    const int*   bat  = (const int*)d_in[4];
    const float* W1   = (const float*)d_in[5];
    const float* b1   = (const float*)d_in[6];
    const float* W2   = (const float*)d_in[7];
    const float* b2   = (const float*)d_in[8];
    const float* W3   = (const float*)d_in[9];
    const float* b3   = (const float*)d_in[10];
    const float* gam  = (const float*)d_in[11];
    const float* bet  = (const float*)d_in[12];
    float* out = (float*)d_out;
    unsigned short* Wp = (unsigned short*)d_ws;   // 458752 B used

    const int E = in_sizes[0] / 128;

    prep_pack<<<896, 256, 0, stream>>>(W1, W2, W3, Wp);
    const int nblk = (E + 63) / 64;
    if ((E & 63) == 0)
        edge_mlp<true><<<nblk, 256, 0, stream>>>(src, dst, ea, u, bat, Wp,
                                                 b1, b2, b3, gam, bet, out, E);
    else
        edge_mlp<false><<<nblk, 256, 0, stream>>>(src, dst, ea, u, bat, Wp,
                                                  b1, b2, b3, gam, bet, out, E);
}